// Round 3
// baseline (552.190 us; speedup 1.0000x reference)
//
#include <hip/hip_runtime.h>
#include <hip/hip_cooperative_groups.h>

namespace cg = cooperative_groups;

#define IMG_H 2048
#define IMG_W 4096
#define CH_ELEMS (IMG_H * IMG_W)        // 8388608 = 2^23
#define CH_N4    (CH_ELEMS / 4)         // 2097152 = 2^21
#define NUM_CH 6
#define SAMPLE_CH 3
#define HBINS 256

// ---- cooperative fused kernel config ----
#define GRID 1024
#define TPB  256
#define NTHREADS (GRID * TPB)           // 262144 = 2^18
#define F4PT (CH_N4 / NTHREADS)         // 8 float4 per thread per channel

// ---- fallback (R2) ws layout ----
#define BPC 512
#define WS_LUT_OFF  (2u << 20)
#define WS_U8_OFF   (4u << 20)

// ======================= fused cooperative kernel ==========================
__global__ __launch_bounds__(TPB, 4) void eq_fused_kernel(
        const float* __restrict__ in, float* __restrict__ out,
        int* __restrict__ gh) {
    cg::grid_group grid = cg::this_grid();
    const int t    = threadIdx.x;
    const int gid  = blockIdx.x * TPB + t;
    const int wave = t >> 6;

    __shared__ int   lh[4][SAMPLE_CH][HBINS];   // 12 KB per-wave sub-hists
    __shared__ float slut[SAMPLE_CH][HBINS];    // 3 KB
    __shared__ int   sc[HBINS];                 // scan
    __shared__ int   sh2[HBINS];                // raw hist copy
    __shared__ int   nzr[HBINS];                // last-nonzero reduce

    for (int i = t; i < 4 * SAMPLE_CH * HBINS; i += TPB) ((int*)lh)[i] = 0;
    if (blockIdx.x == 0)
        for (int i = t; i < SAMPLE_CH * HBINS; i += TPB) gh[i] = 0;
    __syncthreads();

    // -------- Phase A: load sample, bin into LDS, keep bins in VGPRs -------
    unsigned pk[SAMPLE_CH][F4PT];
    const float4* in4 = (const float4*)in;
    #pragma unroll
    for (int ch = 0; ch < SAMPLE_CH; ch++) {
        #pragma unroll
        for (int j = 0; j < F4PT; j++) {
            float4 v = in4[(size_t)ch * CH_N4 + j * NTHREADS + gid];
            int b0 = (int)v.x; b0 = min(max(b0, 0), 255);
            int b1 = (int)v.y; b1 = min(max(b1, 0), 255);
            int b2 = (int)v.z; b2 = min(max(b2, 0), 255);
            int b3 = (int)v.w; b3 = min(max(b3, 0), 255);
            atomicAdd(&lh[wave][ch][b0], 1);
            atomicAdd(&lh[wave][ch][b1], 1);
            atomicAdd(&lh[wave][ch][b2], 1);
            atomicAdd(&lh[wave][ch][b3], 1);
            pk[ch][j] = (unsigned)b0 | ((unsigned)b1 << 8) |
                        ((unsigned)b2 << 16) | ((unsigned)b3 << 24);
        }
    }
    __syncthreads();

    grid.sync();        // gh zeroed before any global atomics

    for (int i = t; i < SAMPLE_CH * HBINS; i += TPB) {
        int ch = i >> 8, b = i & 255;
        int s = lh[0][ch][b] + lh[1][ch][b] + lh[2][ch][b] + lh[3][ch][b];
        if (s) atomicAdd(&gh[i], s);
    }

    grid.sync();        // global hist complete

    // -------- Phase B1: every block rebuilds the 3 LUTs (redundant, cheap) -
    for (int ch = 0; ch < SAMPLE_CH; ch++) {
        int h = gh[ch * HBINS + t];
        sh2[t] = h; sc[t] = h; nzr[t] = (h > 0) ? t : 0;
        __syncthreads();
        for (int off = 1; off < HBINS; off <<= 1) {
            int add = (t >= off) ? sc[t - off] : 0;
            __syncthreads();
            sc[t] += add;
            __syncthreads();
        }
        for (int off = HBINS / 2; off >= 1; off >>= 1) {
            if (t < off) nzr[t] = max(nzr[t], nzr[t + off]);
            __syncthreads();
        }
        const int total   = sc[HBINS - 1];
        const int last_nz = nzr[0];
        const int step    = (total - sh2[last_nz]) / (HBINS - 1);
        float ov;
        if (step == 0)      ov = (float)t;              // identity on bins
        else if (t == 0)    ov = 0.0f;                  // concat([0], lut[:-1])
        else                ov = (float)min((sc[t - 1] + (step >> 1)) / step, 255);
        slut[ch][t] = ov;
        __syncthreads();
    }

    // -------- Phase B2: apply LUT from registers + stream targets ----------
    float4* out4 = (float4*)out;
    #pragma unroll
    for (int ch = 0; ch < SAMPLE_CH; ch++) {
        const float* l = slut[ch];
        #pragma unroll
        for (int j = 0; j < F4PT; j++) {
            unsigned w = pk[ch][j];
            float4 o;
            o.x = l[w & 255u];
            o.y = l[(w >> 8) & 255u];
            o.z = l[(w >> 16) & 255u];
            o.w = l[w >> 24];
            out4[(size_t)ch * CH_N4 + j * NTHREADS + gid] = o;
        }
    }
    #pragma unroll
    for (int ch = SAMPLE_CH; ch < NUM_CH; ch++) {
        #pragma unroll
        for (int j = 0; j < F4PT; j++) {
            size_t idx = (size_t)ch * CH_N4 + j * NTHREADS + gid;
            out4[idx] = in4[idx];
        }
    }
}

// ======================= fallback path (proven R2 kernels) =================
__global__ __launch_bounds__(256) void eq_pass1_kernel(
        const float* __restrict__ in, float* __restrict__ out,
        unsigned* __restrict__ u8buf, int* __restrict__ parts) {
    const int t   = threadIdx.x;
    const int ch  = blockIdx.x / BPC;
    const int blk = blockIdx.x % BPC;

    if (ch >= SAMPLE_CH) {
        const float4* src = (const float4*)(in + (size_t)ch * CH_ELEMS);
        float4*       dst = (float4*)(out + (size_t)ch * CH_ELEMS);
        for (int i = blk * 256 + t; i < CH_N4; i += BPC * 256)
            dst[i] = src[i];
        return;
    }

    __shared__ int lh[4][HBINS];
    const int wave = t >> 6;
    for (int i = t; i < 4 * HBINS; i += 256) ((int*)lh)[i] = 0;
    __syncthreads();

    const float4* src = (const float4*)(in + (size_t)ch * CH_ELEMS);
    unsigned*     dst = u8buf + ch * CH_N4;

    for (int i = blk * 256 + t; i < CH_N4; i += BPC * 256) {
        float4 v = src[i];
        int b0 = (int)v.x; b0 = min(max(b0, 0), 255);
        int b1 = (int)v.y; b1 = min(max(b1, 0), 255);
        int b2 = (int)v.z; b2 = min(max(b2, 0), 255);
        int b3 = (int)v.w; b3 = min(max(b3, 0), 255);
        atomicAdd(&lh[wave][b0], 1);
        atomicAdd(&lh[wave][b1], 1);
        atomicAdd(&lh[wave][b2], 1);
        atomicAdd(&lh[wave][b3], 1);
        dst[i] = (unsigned)b0 | ((unsigned)b1 << 8) |
                 ((unsigned)b2 << 16) | ((unsigned)b3 << 24);
    }
    __syncthreads();

    parts[((size_t)ch * BPC + blk) * HBINS + t] =
        lh[0][t] + lh[1][t] + lh[2][t] + lh[3][t];
}

__global__ __launch_bounds__(256) void eq_lut_kernel(
        const int* __restrict__ parts, float* __restrict__ glut) {
    const int ch = blockIdx.x;
    const int t  = threadIdx.x;
    const int* p = parts + (size_t)ch * BPC * HBINS;

    int h = 0;
    #pragma unroll 8
    for (int j = 0; j < BPC; j++) h += p[j * HBINS + t];

    __shared__ int sh[HBINS];
    __shared__ int sc[HBINS];
    __shared__ int nz[HBINS];
    sh[t] = h; sc[t] = h; nz[t] = (h > 0) ? t : 0;
    __syncthreads();

    for (int off = 1; off < HBINS; off <<= 1) {
        int add = (t >= off) ? sc[t - off] : 0;
        __syncthreads();
        sc[t] += add;
        __syncthreads();
    }
    for (int off = HBINS / 2; off >= 1; off >>= 1) {
        if (t < off) nz[t] = max(nz[t], nz[t + off]);
        __syncthreads();
    }

    const int total   = sc[HBINS - 1];
    const int last_nz = nz[0];
    const int step    = (total - sh[last_nz]) / (HBINS - 1);

    float outv;
    if (step == 0)      outv = (float)t;
    else if (t == 0)    outv = 0.0f;
    else                outv = (float)min((sc[t - 1] + (step >> 1)) / step, 255);
    glut[ch * HBINS + t] = outv;
}

__global__ __launch_bounds__(256) void eq_apply_kernel(
        const unsigned* __restrict__ u8buf, const float* __restrict__ glut,
        float* __restrict__ out) {
    __shared__ float sl[SAMPLE_CH * HBINS];
    for (int i = threadIdx.x; i < SAMPLE_CH * HBINS; i += 256)
        sl[i] = glut[i];
    __syncthreads();

    float4* out4 = (float4*)out;
    const int n = SAMPLE_CH * CH_N4;

    for (int i = blockIdx.x * 256 + threadIdx.x; i < n; i += gridDim.x * 256) {
        unsigned w = u8buf[i];
        const float* l = sl + (i >> 21) * HBINS;
        float4 o;
        o.x = l[w & 255u];
        o.y = l[(w >> 8) & 255u];
        o.z = l[(w >> 16) & 255u];
        o.w = l[w >> 24];
        out4[i] = o;
    }
}

extern "C" void kernel_launch(void* const* d_in, const int* in_sizes, int n_in,
                              void* d_out, int out_size, void* d_ws, size_t ws_size,
                              hipStream_t stream) {
    const float* image = (const float*)d_in[0];
    float* out = (float*)d_out;
    int* gh = (int*)d_ws;                      // 3*256 ints, zeroed in-kernel

    void* args[] = { (void*)&image, (void*)&out, (void*)&gh };
    hipError_t err = hipLaunchCooperativeKernel(
        (const void*)eq_fused_kernel, dim3(GRID), dim3(TPB), args, 0, stream);

    if (err != hipSuccess) {
        // fallback: proven 3-kernel path
        int*      parts = (int*)((char*)d_ws + (16u << 10));
        float*    lut   = (float*)((char*)d_ws + WS_LUT_OFF);
        unsigned* u8buf = (unsigned*)((char*)d_ws + WS_U8_OFF);
        eq_pass1_kernel<<<NUM_CH * BPC, 256, 0, stream>>>(image, out, u8buf, parts);
        eq_lut_kernel<<<SAMPLE_CH, 256, 0, stream>>>(parts, lut);
        eq_apply_kernel<<<2048, 256, 0, stream>>>(u8buf, lut, out);
    }
}